// Round 14
// baseline (127.631 us; speedup 1.0000x reference)
//
#include <hip/hip_runtime.h>

#define HH 160
#define WW 160
#define DD 16
#define NG 8192
#define VOXEL 0.4f

// tiles: 20 x 20 x 4 (each 8x8x4 voxels) = 1600 tiles
#define TTX 20
#define TTY 20
#define TTZ 4
#define NTILES (TTX * TTY * TTZ)
#define CAP 128   // survivors per tile: lambda ~61, P(>128) ~ 8.6 sigma -> safe

// d_ws layout:
//   tileCnt  : NTILES int (6.4 KB)                @ 0
//   tilePack : NTILES * CAP * 4 float4 (13.1 MB)  @ 64 KB
// tilePack record (4 float4 = 64 B):
//   [0] = (mu.x, mu.y, mu.z, opacity)
//   [1] = (3sx,  3sy,  3sz,  as_float(g))   <- gate data, always read
//   [2] = (ci00, ci01, ci02, ci11)          <- read only when __any(pass)
//   [3] = (ci12, ci22, 0, 0)

__global__ __launch_bounds__(64) void gv_precompute_bin(
    const float* __restrict__ means, const float* __restrict__ opac,
    const float* __restrict__ scales, const float* __restrict__ rots,
    int* __restrict__ tileCnt, float4* __restrict__ tilePack) {
  int g = blockIdx.x * 64 + threadIdx.x;
  if (g >= NG) return;
  float qw = rots[g * 4 + 0], qx = rots[g * 4 + 1];
  float qy = rots[g * 4 + 2], qz = rots[g * 4 + 3];
  float inv = rsqrtf(qw * qw + qx * qx + qy * qy + qz * qz);
  qw *= inv; qx *= inv; qy *= inv; qz *= inv;
  float R[3][3];
  R[0][0] = 1.f - 2.f * (qy * qy + qz * qz);
  R[0][1] = 2.f * (qx * qy - qw * qz);
  R[0][2] = 2.f * (qx * qz + qw * qy);
  R[1][0] = 2.f * (qx * qy + qw * qz);
  R[1][1] = 1.f - 2.f * (qx * qx + qz * qz);
  R[1][2] = 2.f * (qy * qz - qw * qx);
  R[2][0] = 2.f * (qx * qz - qw * qy);
  R[2][1] = 2.f * (qy * qz + qw * qx);
  R[2][2] = 1.f - 2.f * (qx * qx + qy * qy);
  float sx = scales[g * 3 + 0], sy = scales[g * 3 + 1], sz = scales[g * 3 + 2];
  float s2[3] = {sx * sx, sy * sy, sz * sz};
  float is2[3] = {1.f / s2[0], 1.f / s2[1], 1.f / s2[2]};
  float cov00 = 0.f, cov11 = 0.f, cov22 = 0.f;
  float ci00 = 0.f, ci01 = 0.f, ci02 = 0.f, ci11 = 0.f, ci12 = 0.f, ci22 = 0.f;
#pragma unroll
  for (int c = 0; c < 3; c++) {
    cov00 += R[0][c] * R[0][c] * s2[c];
    cov11 += R[1][c] * R[1][c] * s2[c];
    cov22 += R[2][c] * R[2][c] * s2[c];
    ci00 += R[0][c] * R[0][c] * is2[c];
    ci01 += R[0][c] * R[1][c] * is2[c];
    ci02 += R[0][c] * R[2][c] * is2[c];
    ci11 += R[1][c] * R[1][c] * is2[c];
    ci12 += R[1][c] * R[2][c] * is2[c];
    ci22 += R[2][c] * R[2][c] * is2[c];
  }
  float mx = means[g * 3 + 0], my = means[g * 3 + 1], mz = means[g * 3 + 2];
  float bx = 3.f * sqrtf(cov00), by = 3.f * sqrtf(cov11), bz = 3.f * sqrtf(cov22);

  const float eps = 1e-4f;
  int i0 = (int)ceilf((mx - bx + 32.f) * 2.5f - 0.5f - eps);
  int i1 = (int)floorf((mx + bx + 32.f) * 2.5f - 0.5f + eps);
  int j0 = (int)ceilf((my - by + 32.f) * 2.5f - 0.5f - eps);
  int j1 = (int)floorf((my + by + 32.f) * 2.5f - 0.5f + eps);
  int k0 = (int)ceilf((mz - bz + 1.f) * 2.5f - 0.5f - eps);
  int k1 = (int)floorf((mz + bz + 1.f) * 2.5f - 0.5f + eps);
  i0 = max(i0, 0); i1 = min(i1, HH - 1);
  j0 = max(j0, 0); j1 = min(j1, WW - 1);
  k0 = max(k0, 0); k1 = min(k1, DD - 1);
  if (i0 > i1 || j0 > j1 || k0 > k1) return;

  float4 p0 = make_float4(mx, my, mz, opac[g]);
  float4 p1 = make_float4(bx, by, bz, __int_as_float(g));
  float4 p2 = make_float4(ci00, ci01, ci02, ci11);
  float4 p3 = make_float4(ci12, ci22, 0.f, 0.f);

  int ti0 = i0 >> 3, ti1 = i1 >> 3;
  int tj0 = j0 >> 3, tj1 = j1 >> 3;
  int tk0 = k0 >> 2, tk1 = k1 >> 2;
  for (int ti = ti0; ti <= ti1; ti++)
    for (int tj = tj0; tj <= tj1; tj++)
      for (int tk = tk0; tk <= tk1; tk++) {
        int t = (ti * TTY + tj) * TTZ + tk;
        int pos = atomicAdd(&tileCnt[t], 1);
        if (pos < CAP) {
          float4* __restrict__ d = tilePack + ((size_t)t * CAP + pos) * 4;
          d[0] = p0;  d[1] = p1;  d[2] = p2;  d[3] = p3;
        }
      }
}

// Voxelize: 2 waves/block, TWO voxels per lane (same i,k; j and j+4).
// LDS broadcast reads per (tile,gaussian) halve vs R13 (2 waves instead of
// 4) -- LDS is the measured bottleneck pipe (~27 of ~30 us). Shared-coord
// math: dx,dz and the dx/dz part of maha computed once per lane; only
// dy-terms per voxel. Feats path unchanged (early uniform s_load by index).
__global__ __launch_bounds__(128) void gv_voxelize(
    const float4* __restrict__ feats, const int* __restrict__ tileCnt,
    const float4* __restrict__ tilePack, float4* __restrict__ out) {
  __shared__ float4 s_pack[CAP * 4];   // 8 KB

  int tid = threadIdx.x;
  int wid = tid >> 6, l = tid & 63;
  int dk = l & 3, dj = (l >> 2) & 3, di = wid * 4 + (l >> 4);
  int tk = blockIdx.x, tj = blockIdx.y, ti = blockIdx.z;
  int i = ti * 8 + di, jA = tj * 8 + dj, jB = jA + 4, k = tk * 4 + dk;

  float px = (i + 0.5f) * VOXEL - 32.f;
  float pyA = (jA + 0.5f) * VOXEL - 32.f;
  float pyB = (jB + 0.5f) * VOXEL - 32.f;
  float pz = (k + 0.5f) * VOXEL - 1.f;

  int t = (ti * TTY + tj) * TTZ + tk;
  int cnt = tileCnt[t];
  cnt = min(cnt, CAP);

  // stage pack records (coalesced, parallel)
  {
    const float4* __restrict__ src = tilePack + (size_t)t * CAP * 4;
    int tot = cnt * 4;
    for (int m = tid; m < tot; m += 128) s_pack[m] = src[m];
  }
  __syncthreads();

  float4 accA[8], accB[8];
#pragma unroll
  for (int f = 0; f < 8; f++) {
    accA[f] = make_float4(0.f, 0.f, 0.f, 0.f);
    accB[f] = make_float4(0.f, 0.f, 0.f, 0.f);
  }

#define GAUSS_BODY(aa, bb, cidx, didx, FF)                                    \
  do {                                                                        \
    float dx = px - aa.x, dz = pz - aa.z;                                     \
    float dyA = pyA - aa.y, dyB = pyB - aa.y;                                 \
    bool okx = (fabsf(dx) <= bb.x) & (fabsf(dz) <= bb.z);                     \
    bool inA = okx & (fabsf(dyA) <= bb.y);                                    \
    bool inB = okx & (fabsf(dyB) <= bb.y);                                    \
    if (__any(inA | inB)) {                                                   \
      float4 cc = s_pack[cidx], dd = s_pack[didx];                            \
      float base = cc.x * dx * dx + dd.y * dz * dz + 2.f * cc.z * dx * dz;    \
      float u = 2.f * (cc.y * dx + dd.x * dz);                                \
      float mA = base + dyA * (cc.w * dyA + u);                               \
      float mB = base + dyB * (cc.w * dyB + u);                               \
      float wA = inA ? aa.w * __expf(-0.5f * mA) : 0.f;                       \
      float wB = inB ? aa.w * __expf(-0.5f * mB) : 0.f;                       \
      _Pragma("unroll")                                                       \
      for (int f = 0; f < 8; f++) {                                           \
        accA[f].x += wA * FF[f].x; accA[f].y += wA * FF[f].y;                 \
        accA[f].z += wA * FF[f].z; accA[f].w += wA * FF[f].w;                 \
        accB[f].x += wB * FF[f].x; accB[f].y += wB * FF[f].y;                 \
        accB[f].z += wB * FF[f].z; accB[f].w += wB * FF[f].w;                 \
      }                                                                       \
    }                                                                         \
  } while (0)

  int n = 0;
  for (; n + 2 <= cnt; n += 2) {
    float4 a0 = s_pack[n * 4 + 0], b0 = s_pack[n * 4 + 1];
    float4 a1 = s_pack[n * 4 + 4], b1 = s_pack[n * 4 + 5];

    int g0 = __builtin_amdgcn_readfirstlane(__float_as_int(b0.w));
    int g1 = __builtin_amdgcn_readfirstlane(__float_as_int(b1.w));
    const float4* __restrict__ fp0 = feats + (size_t)g0 * 8;
    const float4* __restrict__ fp1 = feats + (size_t)g1 * 8;
    float4 F0[8], F1[8];
#pragma unroll
    for (int f = 0; f < 8; f++) F0[f] = fp0[f];
#pragma unroll
    for (int f = 0; f < 8; f++) F1[f] = fp1[f];

    GAUSS_BODY(a0, b0, n * 4 + 2, n * 4 + 3, F0);
    GAUSS_BODY(a1, b1, n * 4 + 6, n * 4 + 7, F1);
  }
  if (n < cnt) {
    float4 pa = s_pack[n * 4 + 0], pb = s_pack[n * 4 + 1];
    int gg = __builtin_amdgcn_readfirstlane(__float_as_int(pb.w));
    const float4* __restrict__ fp = feats + (size_t)gg * 8;
    float4 FT[8];
#pragma unroll
    for (int f = 0; f < 8; f++) FT[f] = fp[f];
    GAUSS_BODY(pa, pb, n * 4 + 2, n * 4 + 3, FT);
  }
#undef GAUSS_BODY

  size_t vA = ((size_t)i * WW + jA) * DD + k;
  size_t vB = ((size_t)i * WW + jB) * DD + k;
  float4* oA = out + vA * 8;
  float4* oB = out + vB * 8;
#pragma unroll
  for (int f = 0; f < 8; f++) oA[f] = accA[f];
#pragma unroll
  for (int f = 0; f < 8; f++) oB[f] = accB[f];
}

extern "C" void kernel_launch(void* const* d_in, const int* in_sizes, int n_in,
                              void* d_out, int out_size, void* d_ws, size_t ws_size,
                              hipStream_t stream) {
  const float* means  = (const float*)d_in[0];
  const float* opac   = (const float*)d_in[1];
  const float* scales = (const float*)d_in[2];
  const float* rots   = (const float*)d_in[3];
  const float4* feats = (const float4*)d_in[4];

  char* ws = (char*)d_ws;
  int* tileCnt     = (int*)ws;                        // 6.4 KB
  float4* tilePack = (float4*)(ws + 64 * 1024);       // 13.1 MB

  hipMemsetAsync(tileCnt, 0, NTILES * sizeof(int), stream);
  gv_precompute_bin<<<128, 64, 0, stream>>>(means, opac, scales, rots,
                                            tileCnt, tilePack);
  dim3 grid(TTZ, TTY, TTX);
  gv_voxelize<<<grid, 128, 0, stream>>>(feats, tileCnt, tilePack,
                                        (float4*)d_out);
}